// Round 9
// baseline (266.431 us; speedup 1.0000x reference)
//
#include <hip/hip_runtime.h>
#include <math.h>

typedef _Float16 h2 __attribute__((ext_vector_type(2)));
typedef _Float16 f16x8 __attribute__((ext_vector_type(8)));
typedef float f32x4 __attribute__((ext_vector_type(4)));

// ws layout (floats):
//   [0, 24576)       T [3][64][128] f32 (b0 folded into axis 0)
//   [24576, 24704)   w0scale[128]
//   [24704, 24832)   w2n[128]
//   [24832, 33024)   Wf: W1n^T f16 B-fragments, 8192 h2

__global__ void precompute_ws(const float* __restrict__ w0v,
                              const float* __restrict__ w0g,
                              const float* __restrict__ w1v,
                              const float* __restrict__ w1g,
                              const float* __restrict__ w2v,
                              const float* __restrict__ w2g,
                              float* __restrict__ w0scale,
                              float* __restrict__ w2n,
                              h2* __restrict__ Wf) {
    __shared__ float s1[128];
    int t = threadIdx.x;
    if (t < 128) {
        float ns = 0.f;
        for (int c = 0; c < 192; ++c) { float v = w0v[t * 192 + c]; ns += v * v; }
        w0scale[t] = w0g[t] / sqrtf(ns);
        float n1 = 0.f;
        for (int k = 0; k < 128; ++k) { float v = w1v[t * 128 + k]; n1 += v * v; }
        s1[t] = w1g[t] / sqrtf(n1);
        float n2 = 0.f;
        for (int k = 0; k < 128; ++k) { float v = w2v[k]; n2 += v * v; }
        w2n[t] = w2v[t] * (w2g[0] / sqrtf(n2));
    }
    __syncthreads();
    for (int pi = t; pi < 8192; pi += 512) {
        int jp = pi & 3;
        int lane = (pi >> 2) & 63;
        int f = pi >> 8;
        int kk = f >> 3, nt = f & 7;
        int n = nt * 16 + (lane & 15);
        int k = kk * 32 + (lane >> 4) * 8 + jp * 2;
        float s = s1[n];
        h2 v;
        v.x = (_Float16)(w1v[n * 128 + k] * s);
        v.y = (_Float16)(w1v[n * 128 + k + 1] * s);
        Wf[pi] = v;
    }
}

__global__ void precompute_T(const float* __restrict__ expr,
                             const float* __restrict__ jqw,
                             const float* __restrict__ flx,
                             const float* __restrict__ fly,
                             const float* __restrict__ flz,
                             const float* __restrict__ w0v,
                             const float* __restrict__ w0scale,
                             const float* __restrict__ b0,
                             float* __restrict__ T) {
    int a = blockIdx.x >> 6;
    int l = blockIdx.x & 63;
    const float* fl = (a == 0) ? flx : (a == 1) ? fly : flz;
    __shared__ float bs[32];
    __shared__ float jaw[32];
    int t = threadIdx.x;
    if (t < 32) {
        float s = 0.f;
        for (int i = 0; i < 80; ++i) s += expr[i] * fl[(i * 64 + l) * 32 + t];
        bs[t] = s;
    } else if (t < 64) {
        int c = t - 32;
        float s = 0.f;
        for (int i = 0; i < 16; ++i) s += jqw[i] * fl[((80 + i) * 64 + l) * 32 + c];
        jaw[c] = s;
    }
    __syncthreads();
    int j = t;
    float acc = 0.f;
    for (int c = 0; c < 32; ++c) acc += w0v[j * 192 + a * 32 + c] * bs[c];
    for (int c = 0; c < 32; ++c) acc += w0v[j * 192 + 96 + a * 32 + c] * jaw[c];
    acc *= w0scale[j];
    if (a == 0) acc += b0[j];
    T[(a * 64 + l) * 128 + j] = acc;
}

// T rows padded to 17 chunks of 16B (272 B): bank-group (r+c) mod 8.
#define T_ROW_CHUNKS 17
#define LDS_T_H2 (192 * T_ROW_CHUNKS * 4)

template <int CTRL>
static __device__ __forceinline__ float dpp_ror_add(float x) {
    int yi = __builtin_amdgcn_update_dpp(0, __builtin_bit_cast(int, x),
                                         CTRL, 0xF, 0xF, false);
    return x + __builtin_bit_cast(float, yi);
}

// Dual-tile per wave: two independent 16-pt tiles per iteration share the
// register-resident B-fragments; their dep chains interleave for ILP.
__launch_bounds__(512)
__attribute__((amdgpu_waves_per_eu(2)))
__global__ void mlp_mfma(const float* __restrict__ xyz,
                         const float* __restrict__ Tg,
                         const f32x4* __restrict__ Wfrag,
                         const float* __restrict__ w2ng,
                         const float* __restrict__ b1,
                         const float* __restrict__ b2p,
                         float* __restrict__ out, int npts) {
    __shared__ __align__(16) h2 tT[LDS_T_H2];
    int tid = threadIdx.x;

    for (int pi = tid; pi < 12288; pi += 512) {
        int r = pi >> 6;
        int p = pi & 63;
        int dst = (r * T_ROW_CHUNKS + (p >> 2)) * 4 + (p & 3);
        h2 v;
        v.x = (_Float16)Tg[2 * pi];
        v.y = (_Float16)Tg[2 * pi + 1];
        tT[dst] = v;
    }
    __syncthreads();

    int lane = tid & 63;
    int lp = lane & 15;
    int lg = lane >> 4;

    // B-fragments pinned (they land in AGPRs; opaque asm blocks remat/sink)
    f32x4 Bf[4][8];
#pragma unroll
    for (int kk = 0; kk < 4; ++kk)
#pragma unroll
        for (int nt = 0; nt < 8; ++nt)
            Bf[kk][nt] = Wfrag[(((kk * 8 + nt) << 6) | lane)];
#pragma unroll
    for (int kk = 0; kk < 4; ++kk)
#pragma unroll
        for (int nt = 0; nt < 8; ++nt)
            asm volatile("" : "+v"(Bf[kk][nt]));

    float b1r[8], w2r[8];
#pragma unroll
    for (int nt = 0; nt < 8; ++nt) {
        b1r[nt] = b1[nt * 16 + lp];
        w2r[nt] = w2ng[nt * 16 + lp];
    }
    float b2 = b2p[0];

    int waveid = blockIdx.x * 8 + (tid >> 6);
    int nwaves = gridDim.x * 8;
    int ntiles = (npts + 15) >> 4;
    int npairs = (ntiles + 1) >> 1;

    // prefetch first pair's xyz
    float cc[2][3];
    {
        int pr = waveid;
        int prc = min(pr, npairs - 1);
#pragma unroll
        for (int u = 0; u < 2; ++u) {
            int pc = min(((prc * 2 + u) << 4) + lp, npts - 1);
            cc[u][0] = xyz[pc * 3 + 0];
            cc[u][1] = xyz[pc * 3 + 1];
            cc[u][2] = xyz[pc * 3 + 2];
        }
    }

#pragma unroll 1
    for (int pair = waveid; pair < npairs; pair += nwaves) {
        // prefetch next pair's xyz (overlaps this pair's compute)
        float nc[2][3];
        {
            int pr = min(pair + nwaves, npairs - 1);
#pragma unroll
            for (int u = 0; u < 2; ++u) {
                int pc = min(((pr * 2 + u) << 4) + lp, npts - 1);
                nc[u][0] = xyz[pc * 3 + 0];
                nc[u][1] = xyz[pc * 3 + 1];
                nc[u][2] = xyz[pc * 3 + 2];
            }
        }

        // ---- A fragments for both tiles ----
        f16x8 hA[2][4];
#pragma unroll
        for (int u = 0; u < 2; ++u)
#pragma unroll
            for (int kk = 0; kk < 4; ++kk)
                hA[u][kk] = (f16x8){0, 0, 0, 0, 0, 0, 0, 0};

#pragma unroll
        for (int u = 0; u < 2; ++u) {
#pragma unroll
            for (int a = 0; a < 3; ++a) {
                float v = cc[u][a];
                v = fminf(fmaxf(v, 0.f), 1.f) * 63.f;
                float fv = floorf(v);
                int li = (int)fv;
                int ri = min(li + 1, 63);
                _Float16 w = (_Float16)(v - fv);
                _Float16 wl = (_Float16)1.0f - w;
                f16x8 w8  = {w, w, w, w, w, w, w, w};
                f16x8 wl8 = {wl, wl, wl, wl, wl, wl, wl, wl};
                int cbL = (a * 64 + li) * T_ROW_CHUNKS;
                int cbR = (a * 64 + ri) * T_ROW_CHUNKS;
#pragma unroll
                for (int kk = 0; kk < 4; ++kk) {
                    int cidx = kk * 4 + lg;
                    f16x8 vl = *reinterpret_cast<const f16x8*>(&tT[(cbL + cidx) << 2]);
                    f16x8 vr = *reinterpret_cast<const f16x8*>(&tT[(cbR + cidx) << 2]);
                    hA[u][kk] = hA[u][kk] + vl * wl8 + vr * w8;
                }
            }
        }
        f16x8 z8 = (f16x8){0, 0, 0, 0, 0, 0, 0, 0};
#pragma unroll
        for (int u = 0; u < 2; ++u)
#pragma unroll
            for (int kk = 0; kk < 4; ++kk)
                hA[u][kk] = __builtin_elementwise_max(hA[u][kk], z8);

        // ---- Layer 1 MFMA, b1 folded into acc init ----
        f32x4 acc[2][8];
#pragma unroll
        for (int u = 0; u < 2; ++u)
#pragma unroll
            for (int nt = 0; nt < 8; ++nt)
                acc[u][nt] = (f32x4){b1r[nt], b1r[nt], b1r[nt], b1r[nt]};

#pragma unroll
        for (int kk = 0; kk < 4; ++kk)
#pragma unroll
            for (int nt = 0; nt < 8; ++nt) {
                acc[0][nt] = __builtin_amdgcn_mfma_f32_16x16x32_f16(
                    hA[0][kk], __builtin_bit_cast(f16x8, Bf[kk][nt]), acc[0][nt], 0, 0, 0);
                acc[1][nt] = __builtin_amdgcn_mfma_f32_16x16x32_f16(
                    hA[1][kk], __builtin_bit_cast(f16x8, Bf[kk][nt]), acc[1][nt], 0, 0, 0);
            }

        // ---- Layer 2 epilogue, both tiles ----
#pragma unroll
        for (int u = 0; u < 2; ++u) {
            int tile = pair * 2 + u;
            float part0 = 0.f, part1 = 0.f, part2 = 0.f, part3 = 0.f;
#pragma unroll
            for (int nt = 0; nt < 8; ++nt) {
                part0 += w2r[nt] * fmaxf(acc[u][nt][0], 0.f);
                part1 += w2r[nt] * fmaxf(acc[u][nt][1], 0.f);
                part2 += w2r[nt] * fmaxf(acc[u][nt][2], 0.f);
                part3 += w2r[nt] * fmaxf(acc[u][nt][3], 0.f);
            }
            part0 = dpp_ror_add<0x128>(part0);
            part1 = dpp_ror_add<0x128>(part1);
            part2 = dpp_ror_add<0x128>(part2);
            part3 = dpp_ror_add<0x128>(part3);
            part0 = dpp_ror_add<0x124>(part0);
            part1 = dpp_ror_add<0x124>(part1);
            part2 = dpp_ror_add<0x124>(part2);
            part3 = dpp_ror_add<0x124>(part3);
            part0 = dpp_ror_add<0x122>(part0);
            part1 = dpp_ror_add<0x122>(part1);
            part2 = dpp_ror_add<0x122>(part2);
            part3 = dpp_ror_add<0x122>(part3);
            part0 = dpp_ror_add<0x121>(part0);
            part1 = dpp_ror_add<0x121>(part1);
            part2 = dpp_ror_add<0x121>(part2);
            part3 = dpp_ror_add<0x121>(part3);

            if (tile < ntiles) {
                int mbase = (tile << 4) + (lg << 2);
                if (lp == 0 && mbase + 0 < npts) out[mbase + 0] = part0 + b2;
                if (lp == 1 && mbase + 1 < npts) out[mbase + 1] = part1 + b2;
                if (lp == 2 && mbase + 2 < npts) out[mbase + 2] = part2 + b2;
                if (lp == 3 && mbase + 3 < npts) out[mbase + 3] = part3 + b2;
            }
        }

#pragma unroll
        for (int u = 0; u < 2; ++u) {
            cc[u][0] = nc[u][0];
            cc[u][1] = nc[u][1];
            cc[u][2] = nc[u][2];
        }
    }
}

extern "C" void kernel_launch(void* const* d_in, const int* in_sizes, int n_in,
                              void* d_out, int out_size, void* d_ws, size_t ws_size,
                              hipStream_t stream) {
    const float* expr = (const float*)d_in[0];
    const float* jqw  = (const float*)d_in[1];
    const float* xyz  = (const float*)d_in[2];
    const float* flx  = (const float*)d_in[3];
    const float* fly  = (const float*)d_in[4];
    const float* flz  = (const float*)d_in[5];
    const float* w0v  = (const float*)d_in[6];
    const float* w0g  = (const float*)d_in[7];
    const float* b0   = (const float*)d_in[8];
    const float* w1v  = (const float*)d_in[9];
    const float* w1g  = (const float*)d_in[10];
    const float* b1   = (const float*)d_in[11];
    const float* w2v  = (const float*)d_in[12];
    const float* w2g  = (const float*)d_in[13];
    const float* b2   = (const float*)d_in[14];

    float* ws = (float*)d_ws;
    float* T       = ws;
    float* w0scale = ws + 24576;
    float* w2n     = ws + 24704;
    h2*    Wf      = (h2*)(ws + 24832);

    int npts = in_sizes[2] / 3;

    precompute_ws<<<1, 512, 0, stream>>>(w0v, w0g, w1v, w1g, w2v, w2g,
                                         w0scale, w2n, Wf);
    precompute_T<<<192, 128, 0, stream>>>(expr, jqw, flx, fly, flz, w0v,
                                          w0scale, b0, T);
    mlp_mfma<<<256, 512, 0, stream>>>(xyz, T, (const f32x4*)Wf, w2n, b1, b2,
                                      (float*)d_out, npts);
}

// Round 10
// 218.211 us; speedup vs baseline: 1.2210x; 1.2210x over previous
//
#include <hip/hip_runtime.h>
#include <math.h>

typedef _Float16 h2 __attribute__((ext_vector_type(2)));
typedef _Float16 f16x8 __attribute__((ext_vector_type(8)));
typedef float f32x4 __attribute__((ext_vector_type(4)));

// ws layout (floats):
//   [0, 24576)       T [3][64][128] f32 (b0 folded into axis 0)
//   [24576, 24704)   w0scale[128]
//   [24704, 24832)   w2n[128]
//   [24832, 33024)   Wf: W1n^T f16 B-fragments, 8192 h2

__global__ void precompute_ws(const float* __restrict__ w0v,
                              const float* __restrict__ w0g,
                              const float* __restrict__ w1v,
                              const float* __restrict__ w1g,
                              const float* __restrict__ w2v,
                              const float* __restrict__ w2g,
                              float* __restrict__ w0scale,
                              float* __restrict__ w2n,
                              h2* __restrict__ Wf) {
    __shared__ float s1[128];
    int t = threadIdx.x;
    if (t < 128) {
        float ns = 0.f;
        for (int c = 0; c < 192; ++c) { float v = w0v[t * 192 + c]; ns += v * v; }
        w0scale[t] = w0g[t] / sqrtf(ns);
        float n1 = 0.f;
        for (int k = 0; k < 128; ++k) { float v = w1v[t * 128 + k]; n1 += v * v; }
        s1[t] = w1g[t] / sqrtf(n1);
        float n2 = 0.f;
        for (int k = 0; k < 128; ++k) { float v = w2v[k]; n2 += v * v; }
        w2n[t] = w2v[t] * (w2g[0] / sqrtf(n2));
    }
    __syncthreads();
    for (int pi = t; pi < 8192; pi += 512) {
        int jp = pi & 3;
        int lane = (pi >> 2) & 63;
        int f = pi >> 8;
        int kk = f >> 3, nt = f & 7;
        int n = nt * 16 + (lane & 15);
        int k = kk * 32 + (lane >> 4) * 8 + jp * 2;
        float s = s1[n];
        h2 v;
        v.x = (_Float16)(w1v[n * 128 + k] * s);
        v.y = (_Float16)(w1v[n * 128 + k + 1] * s);
        Wf[pi] = v;
    }
}

__global__ void precompute_T(const float* __restrict__ expr,
                             const float* __restrict__ jqw,
                             const float* __restrict__ flx,
                             const float* __restrict__ fly,
                             const float* __restrict__ flz,
                             const float* __restrict__ w0v,
                             const float* __restrict__ w0scale,
                             const float* __restrict__ b0,
                             float* __restrict__ T) {
    int a = blockIdx.x >> 6;
    int l = blockIdx.x & 63;
    const float* fl = (a == 0) ? flx : (a == 1) ? fly : flz;
    __shared__ float bs[32];
    __shared__ float jaw[32];
    int t = threadIdx.x;
    if (t < 32) {
        float s = 0.f;
        for (int i = 0; i < 80; ++i) s += expr[i] * fl[(i * 64 + l) * 32 + t];
        bs[t] = s;
    } else if (t < 64) {
        int c = t - 32;
        float s = 0.f;
        for (int i = 0; i < 16; ++i) s += jqw[i] * fl[((80 + i) * 64 + l) * 32 + c];
        jaw[c] = s;
    }
    __syncthreads();
    int j = t;
    float acc = 0.f;
    for (int c = 0; c < 32; ++c) acc += w0v[j * 192 + a * 32 + c] * bs[c];
    for (int c = 0; c < 32; ++c) acc += w0v[j * 192 + 96 + a * 32 + c] * jaw[c];
    acc *= w0scale[j];
    if (a == 0) acc += b0[j];
    T[(a * 64 + l) * 128 + j] = acc;
}

// U table in LDS: per row r (192 rows), 32 interleaved 16B chunks:
//   chunk 2c   = T[r], halfs 8c..8c+7   (f16)
//   chunk 2c+1 = T[r+1]-T[r] same halfs (0 for local row 63 -> clamp semantics)
// Row stride = 33 chunks (528 B): bank-group (4r + 4c) mod 32 spreads rows.
#define U_ROW_CHUNKS 33
#define LDS_U_H2 (192 * U_ROW_CHUNKS * 4)   // 25344 h2 = 101376 B

template <int CTRL>
static __device__ __forceinline__ float dpp_ror_add(float x) {
    int yi = __builtin_amdgcn_update_dpp(0, __builtin_bit_cast(int, x),
                                         CTRL, 0xF, 0xF, false);
    return x + __builtin_bit_cast(float, yi);
}

__launch_bounds__(512)
__attribute__((amdgpu_waves_per_eu(2)))   // 256 unified regs/wave: 128 Bf + 32 acc + ~96 arch
__global__ void mlp_mfma(const float* __restrict__ xyz,
                         const float* __restrict__ Tg,
                         const f32x4* __restrict__ Wfrag,
                         const float* __restrict__ w2ng,
                         const float* __restrict__ b1,
                         const float* __restrict__ b2p,
                         float* __restrict__ out, int npts) {
    __shared__ __align__(16) h2 tT[LDS_U_H2];
    int tid = threadIdx.x;

    // Stage T (f32) -> interleaved {T, delta} f16 chunks.
    for (int u = tid; u < 12288; u += 512) {
        int r = u >> 6;        // 0..191
        int p = u & 63;        // h2-pair within row
        int rl = r & 63;
        float t0 = Tg[2 * u], t1 = Tg[2 * u + 1];
        float d0 = 0.f, d1 = 0.f;
        if (rl != 63) {
            d0 = Tg[2 * u + 128] - t0;
            d1 = Tg[2 * u + 129] - t1;
        }
        int base = (r * U_ROW_CHUNKS + 2 * (p >> 2)) * 4 + (p & 3);
        h2 tv; tv.x = (_Float16)t0; tv.y = (_Float16)t1;
        h2 dv; dv.x = (_Float16)d0; dv.y = (_Float16)d1;
        tT[base] = tv;       // T chunk
        tT[base + 4] = dv;   // delta chunk (next 16B)
    }
    __syncthreads();

    int lane = tid & 63;
    int lp = lane & 15;
    int lg = lane >> 4;

    // Layer-1 B-fragments pinned in registers (unified-file AGPRs).
    f32x4 Bf[4][8];
#pragma unroll
    for (int kk = 0; kk < 4; ++kk)
#pragma unroll
        for (int nt = 0; nt < 8; ++nt)
            Bf[kk][nt] = Wfrag[(((kk * 8 + nt) << 6) | lane)];
#pragma unroll
    for (int kk = 0; kk < 4; ++kk)
#pragma unroll
        for (int nt = 0; nt < 8; ++nt)
            asm volatile("" : "+v"(Bf[kk][nt]));

    float b1r[8], w2r[8];
#pragma unroll
    for (int nt = 0; nt < 8; ++nt) {
        b1r[nt] = b1[nt * 16 + lp];
        w2r[nt] = w2ng[nt * 16 + lp];
    }
    float b2 = b2p[0];

    int waveid = blockIdx.x * 8 + (tid >> 6);
    int nwaves = gridDim.x * 8;
    int ntiles = (npts + 15) >> 4;

    // prefetch first tile's xyz
    float cx, cy, cz;
    {
        int pc = min((min(waveid, ntiles - 1) << 4) + lp, npts - 1);
        cx = xyz[pc * 3 + 0];
        cy = xyz[pc * 3 + 1];
        cz = xyz[pc * 3 + 2];
    }

#pragma unroll 1
    for (int tile = waveid; tile < ntiles; tile += nwaves) {
        // prefetch next tile's xyz (hides under this tile's compute)
        float nx, ny, nz;
        {
            int pr = min(tile + nwaves, ntiles - 1);
            int pc = min((pr << 4) + lp, npts - 1);
            nx = xyz[pc * 3 + 0];
            ny = xyz[pc * 3 + 1];
            nz = xyz[pc * 3 + 2];
        }

        // ---- A fragments: hA[kk] = relu(h0[pt lp][kk*32 + lg*8 + 0..7]) ----
        f16x8 hA[4];
#pragma unroll
        for (int a = 0; a < 3; ++a) {
            float v = (a == 0) ? cx : (a == 1) ? cy : cz;
            v = fminf(fmaxf(v, 0.f), 1.f) * 63.f;
            float fv = floorf(v);
            int li = (int)fv;
            _Float16 w = (_Float16)(v - fv);
            f16x8 w8 = {w, w, w, w, w, w, w, w};
            int Rb = (a * 64 + li) * U_ROW_CHUNKS;
#pragma unroll
            for (int kk = 0; kk < 4; ++kk) {
                int ci = Rb + 2 * (kk * 4 + lg);
                f16x8 t8 = *reinterpret_cast<const f16x8*>(&tT[ci * 4]);
                f16x8 d8 = *reinterpret_cast<const f16x8*>(&tT[ci * 4 + 4]);
                if (a == 0)
                    hA[kk] = t8 + w8 * d8;           // v_pk_fma
                else
                    hA[kk] = hA[kk] + (t8 + w8 * d8);
            }
        }
        f16x8 z8 = (f16x8){0, 0, 0, 0, 0, 0, 0, 0};
#pragma unroll
        for (int kk = 0; kk < 4; ++kk)
            hA[kk] = __builtin_elementwise_max(hA[kk], z8);

        // ---- Layer 1 MFMA, b1 folded into acc init ----
        f32x4 acc[8];
#pragma unroll
        for (int nt = 0; nt < 8; ++nt)
            acc[nt] = (f32x4){b1r[nt], b1r[nt], b1r[nt], b1r[nt]};

#pragma unroll
        for (int kk = 0; kk < 4; ++kk)
#pragma unroll
            for (int nt = 0; nt < 8; ++nt)
                acc[nt] = __builtin_amdgcn_mfma_f32_16x16x32_f16(
                    hA[kk], __builtin_bit_cast(f16x8, Bf[kk][nt]), acc[nt], 0, 0, 0);

        // ---- Layer 2 + epilogue ----
        float part0 = 0.f, part1 = 0.f, part2 = 0.f, part3 = 0.f;
#pragma unroll
        for (int nt = 0; nt < 8; ++nt) {
            part0 += w2r[nt] * fmaxf(acc[nt][0], 0.f);
            part1 += w2r[nt] * fmaxf(acc[nt][1], 0.f);
            part2 += w2r[nt] * fmaxf(acc[nt][2], 0.f);
            part3 += w2r[nt] * fmaxf(acc[nt][3], 0.f);
        }
        part0 = dpp_ror_add<0x128>(part0);
        part1 = dpp_ror_add<0x128>(part1);
        part2 = dpp_ror_add<0x128>(part2);
        part3 = dpp_ror_add<0x128>(part3);
        part0 = dpp_ror_add<0x124>(part0);
        part1 = dpp_ror_add<0x124>(part1);
        part2 = dpp_ror_add<0x124>(part2);
        part3 = dpp_ror_add<0x124>(part3);
        part0 = dpp_ror_add<0x122>(part0);
        part1 = dpp_ror_add<0x122>(part1);
        part2 = dpp_ror_add<0x122>(part2);
        part3 = dpp_ror_add<0x122>(part3);
        part0 = dpp_ror_add<0x121>(part0);
        part1 = dpp_ror_add<0x121>(part1);
        part2 = dpp_ror_add<0x121>(part2);
        part3 = dpp_ror_add<0x121>(part3);

        // lane lp<4 stores out[m0 + 4*lg + lp]
        float sel = part3;
        sel = (lp == 2) ? part2 : sel;
        sel = (lp == 1) ? part1 : sel;
        sel = (lp == 0) ? part0 : sel;
        int mi = (tile << 4) + (lg << 2) + lp;
        if (lp < 4 && mi < npts) out[mi] = sel + b2;

        cx = nx; cy = ny; cz = nz;
    }
}

extern "C" void kernel_launch(void* const* d_in, const int* in_sizes, int n_in,
                              void* d_out, int out_size, void* d_ws, size_t ws_size,
                              hipStream_t stream) {
    const float* expr = (const float*)d_in[0];
    const float* jqw  = (const float*)d_in[1];
    const float* xyz  = (const float*)d_in[2];
    const float* flx  = (const float*)d_in[3];
    const float* fly  = (const float*)d_in[4];
    const float* flz  = (const float*)d_in[5];
    const float* w0v  = (const float*)d_in[6];
    const float* w0g  = (const float*)d_in[7];
    const float* b0   = (const float*)d_in[8];
    const float* w1v  = (const float*)d_in[9];
    const float* w1g  = (const float*)d_in[10];
    const float* b1   = (const float*)d_in[11];
    const float* w2v  = (const float*)d_in[12];
    const float* w2g  = (const float*)d_in[13];
    const float* b2   = (const float*)d_in[14];

    float* ws = (float*)d_ws;
    float* T       = ws;
    float* w0scale = ws + 24576;
    float* w2n     = ws + 24704;
    h2*    Wf      = (h2*)(ws + 24832);

    int npts = in_sizes[2] / 3;

    precompute_ws<<<1, 512, 0, stream>>>(w0v, w0g, w1v, w1g, w2v, w2g,
                                         w0scale, w2n, Wf);
    precompute_T<<<192, 128, 0, stream>>>(expr, jqw, flx, fly, flz, w0v,
                                          w0scale, b0, T);
    mlp_mfma<<<256, 512, 0, stream>>>(xyz, T, (const f32x4*)Wf, w2n, b1, b2,
                                      (float*)d_out, npts);
}